// Round 2
// baseline (706.777 us; speedup 1.0000x reference)
//
#include <hip/hip_runtime.h>

#define S_LEN 920
#define DMODEL 1536
#define NH 4
#define HD 384
#define LREL 1839
#define BATCH 8
#define MTOT (BATCH * S_LEN)   // 7360
#define KPAD 960               // padded key-dim for PV gemm
#define TSTRIDE 1840           // padded L stride for T
#define NBH (BATCH * NH)       // 32
#define CHUNK 8                // bh per chunk = 2 batches
#define NCHUNK 4

// ---- Q/K live inside d_out (shorts). Per 2-batch chunk c, bytes
// [c*11304960, (c+1)*11304960) hold [Q(2c),K(2c),Q(2c+1),K(2c+1)]; chunk c's
// ctx output overwrites exactly this region AFTER its scores GEMM consumed it.
#define CHS   5652480UL        // chunk stride in shorts
#define BSLAB 2826240UL        // per-batch Q+K slab in shorts
#define KOFF  1413120UL        // K offset within batch slab (shorts)

// ---- ws layout (bytes), total 93,306,112 ----
#define XB_OFF  0UL            // X bf16 22,609,920   (dead after qkv)
#define WT_OFF  22609920UL     // Wt bf16 14,155,776  (dead after qkv)
#define TC_OFF  0UL            // T chunk bf16 27,084,800   (aliases Xb/Wt)
#define SCC_OFF 27084800UL     // SC chunk fp32 27,084,800
#define PRC_OFF 54169600UL     // PR chunk bf16 14,131,200
#define EB_OFF  68300800UL     // E bf16 1,412,352
#define VT_OFF  69713152UL     // Vt bf16 23,592,960

typedef __attribute__((ext_vector_type(8))) short  s16x8;
typedef __attribute__((ext_vector_type(4))) short  s16x4;
typedef __attribute__((ext_vector_type(8))) __bf16 bf16x8;
typedef __attribute__((ext_vector_type(4))) float  f32x4;

__device__ __forceinline__ short f2b(float x) {
  unsigned u = __builtin_bit_cast(unsigned, x);
  unsigned r = (u + 0x7FFFu + ((u >> 16) & 1u)) >> 16;
  return (short)r;
}
__device__ __forceinline__ float b2f(short s) {
  unsigned u = ((unsigned)(unsigned short)s) << 16;
  return __builtin_bit_cast(float, u);
}

__device__ __forceinline__ void load_lds16(const short* g, short* lds) {
  __builtin_amdgcn_global_load_lds(
      (const __attribute__((address_space(1))) void*)g,
      (__attribute__((address_space(3))) void*)lds, 16, 0, 0);
}

__device__ __forceinline__ f32x4 mfma_bf16(s16x8 a, s16x8 b, f32x4 c) {
  return __builtin_amdgcn_mfma_f32_16x16x32_bf16(
      __builtin_bit_cast(bf16x8, a), __builtin_bit_cast(bf16x8, b), c, 0, 0, 0);
}

// ---------------------------------------------------------------------------
// 128x128 tile GEMM, C = A * B(NxK row-major)^T.  K multiple of 64.
// Staged row indices clamped to [0,mClamp]/[0,nClamp] (relative to base).
// acc[i][j][r] = C[m0+wm+i*16+(lane>>4)*4+r][n0+wn+j*16+(lane&15)]
// ---------------------------------------------------------------------------
__device__ __forceinline__ void gemm_core(const short* __restrict__ A, int ldA, int mClamp,
                                          const short* __restrict__ B, int ldB, int nClamp,
                                          int K, int m0, int n0, f32x4 acc[4][4]) {
  __shared__ short As[128 * 64];
  __shared__ short Bs[128 * 64];

  const int tid  = threadIdx.x;
  const int w    = tid >> 6;
  const int lane = tid & 63;
  const int lrow = lane >> 3;
  const int lcol = (lane & 7) * 8;
  const int lr   = lane & 15;
  const int lq   = lane >> 4;
  const int wm   = (w >> 1) * 64;
  const int wn   = (w & 1) * 64;

#pragma unroll
  for (int i = 0; i < 4; ++i)
#pragma unroll
    for (int j = 0; j < 4; ++j) acc[i][j] = (f32x4){0.f, 0.f, 0.f, 0.f};

  for (int k0 = 0; k0 < K; k0 += 64) {
#pragma unroll
    for (int i = 0; i < 4; ++i) {
      int row = w * 32 + i * 8 + lrow;
      int ra = m0 + row; if (ra > mClamp) ra = mClamp;
      load_lds16(A + (size_t)ra * ldA + k0 + lcol, &As[(w * 32 + i * 8) * 64]);
      int rb = n0 + row; if (rb > nClamp) rb = nClamp;
      load_lds16(B + (size_t)rb * ldB + k0 + lcol, &Bs[(w * 32 + i * 8) * 64]);
    }
    __syncthreads();
#pragma unroll
    for (int kk = 0; kk < 2; ++kk) {
      s16x8 af[4], bf[4];
#pragma unroll
      for (int f = 0; f < 4; ++f)
        af[f] = *(const s16x8*)&As[(wm + f * 16 + lr) * 64 + kk * 32 + lq * 8];
#pragma unroll
      for (int f = 0; f < 4; ++f)
        bf[f] = *(const s16x8*)&Bs[(wn + f * 16 + lr) * 64 + kk * 32 + lq * 8];
#pragma unroll
      for (int i = 0; i < 4; ++i)
#pragma unroll
        for (int j = 0; j < 4; ++j)
          acc[i][j] = mfma_bf16(af[i], bf[j], acc[i][j]);
    }
    __syncthreads();
  }
}

// ---------------------------------------------------------------------------
__global__ void k_cast(const float* __restrict__ X, short* __restrict__ O, int n4) {
  int i = blockIdx.x * blockDim.x + threadIdx.x;
  if (i >= n4) return;
  float4 v = ((const float4*)X)[i];
  s16x4 o = {f2b(v.x), f2b(v.y), f2b(v.z), f2b(v.w)};
  *(s16x4*)&O[(size_t)i * 4] = o;
}

__global__ void k_transpose_w(const float* __restrict__ W0, const float* __restrict__ W1,
                              const float* __restrict__ W2, short* __restrict__ Wt) {
  const float* W = (blockIdx.z == 0) ? W0 : ((blockIdx.z == 1) ? W1 : W2);
  short* O = Wt + (size_t)blockIdx.z * DMODEL * DMODEL;
  __shared__ float t[32][33];
  int tx = threadIdx.x, ty = threadIdx.y;
  int n0 = blockIdx.x * 32, k0 = blockIdx.y * 32;
#pragma unroll
  for (int i = 0; i < 4; ++i)
    t[ty + i * 8][tx] = W[(size_t)(k0 + ty + i * 8) * DMODEL + n0 + tx];
  __syncthreads();
#pragma unroll
  for (int i = 0; i < 4; ++i)
    O[(size_t)(n0 + ty + i * 8) * DMODEL + k0 + tx] = f2b(t[tx][ty + i * 8]);
}

__global__ void k_zero_vtpad(short* __restrict__ Vt) {
  int idx = blockIdx.x * blockDim.x + threadIdx.x;
  if (idx >= NBH * HD * (KPAD - S_LEN)) return;
  int bhd = idx / (KPAD - S_LEN);
  int s = S_LEN + idx - bhd * (KPAD - S_LEN);
  Vt[(size_t)bhd * KPAD + s] = 0;
}

// ---------------------------------------------------------------------------
__global__ __launch_bounds__(256) void k_gemm_qkv(const short* __restrict__ Xb,
                                                  const short* __restrict__ Wt,
                                                  short* __restrict__ out16,
                                                  short* __restrict__ Vt) {
  const int z = blockIdx.z;
  const int m0 = blockIdx.x * 128, n0 = blockIdx.y * 128;
  f32x4 acc[4][4];
  gemm_core(Xb, DMODEL, MTOT - 1, Wt + (size_t)z * DMODEL * DMODEL, DMODEL,
            DMODEL - 1, DMODEL, m0, n0, acc);
  const int tid = threadIdx.x, w = tid >> 6, lane = tid & 63;
  const int lr = lane & 15, lq = lane >> 4;
  const int wm = (w >> 1) * 64, wn = (w & 1) * 64;
  const float inv = 0.05103103630798287f;  // 1/sqrt(384)
#pragma unroll
  for (int i = 0; i < 4; ++i)
#pragma unroll
    for (int j = 0; j < 4; ++j) {
      int n = n0 + wn + j * 16 + lr;
#pragma unroll
      for (int r = 0; r < 4; ++r) {
        int m = m0 + wm + i * 16 + lq * 4 + r;
        if (m >= MTOT) continue;
        float v = acc[i][j][r];
        int b = m / S_LEN, s = m - b * S_LEN;
        if (z == 2) {
          int h = n / HD, d = n - h * HD;
          Vt[(((size_t)(b * NH + h)) * HD + d) * KPAD + s] = f2b(v);
        } else {
          short* dst = out16 + (size_t)(b >> 1) * CHS + (size_t)(b & 1) * BSLAB +
                       (z == 1 ? KOFF : 0UL);
          dst[(size_t)s * DMODEL + n] = f2b(z == 0 ? v * inv : v);
        }
      }
    }
}

__global__ __launch_bounds__(256) void k_gemm_T(const short* __restrict__ out16,
                                                const short* __restrict__ Eb,
                                                short* __restrict__ Tc, int c) {
  const int z = blockIdx.z;                 // local bh in chunk
  const int bh = c * CHUNK + z, b = bh >> 2, h = bh & 3;
  const int m0 = blockIdx.x * 128, n0 = blockIdx.y * 128;
  const short* A = out16 + (size_t)(b >> 1) * CHS + (size_t)(b & 1) * BSLAB + h * HD;
  f32x4 acc[4][4];
  gemm_core(A, DMODEL, S_LEN - 1, Eb, HD, LREL - 1, HD, m0, n0, acc);
  const int tid = threadIdx.x, w = tid >> 6, lane = tid & 63;
  const int lr = lane & 15, lq = lane >> 4;
  const int wm = (w >> 1) * 64, wn = (w & 1) * 64;
#pragma unroll
  for (int i = 0; i < 4; ++i)
#pragma unroll
    for (int j = 0; j < 4; ++j) {
      int n = n0 + wn + j * 16 + lr;
#pragma unroll
      for (int r = 0; r < 4; ++r) {
        int m = m0 + wm + i * 16 + lq * 4 + r;
        if (m < S_LEN && n < LREL)
          Tc[((size_t)z * S_LEN + m) * TSTRIDE + n] = f2b(acc[i][j][r]);
      }
    }
}

__global__ __launch_bounds__(256) void k_gemm_scores(const short* __restrict__ out16,
                                                     const short* __restrict__ Tc,
                                                     float* __restrict__ SCc, int c) {
  const int z = blockIdx.z;
  const int bh = c * CHUNK + z, b = bh >> 2, h = bh & 3;
  const int m0 = blockIdx.x * 128, n0 = blockIdx.y * 128;
  const short* Qp = out16 + (size_t)(b >> 1) * CHS + (size_t)(b & 1) * BSLAB + h * HD;
  const short* Kp = Qp + KOFF;
  f32x4 acc[4][4];
  gemm_core(Qp, DMODEL, S_LEN - 1, Kp, DMODEL, S_LEN - 1, HD, m0, n0, acc);
  const int tid = threadIdx.x, w = tid >> 6, lane = tid & 63;
  const int lr = lane & 15, lq = lane >> 4;
  const int wm = (w >> 1) * 64, wn = (w & 1) * 64;
#pragma unroll
  for (int i = 0; i < 4; ++i)
#pragma unroll
    for (int j = 0; j < 4; ++j) {
      int n = n0 + wn + j * 16 + lr;
#pragma unroll
      for (int r = 0; r < 4; ++r) {
        int m = m0 + wm + i * 16 + lq * 4 + r;
        if (m < S_LEN && n < S_LEN) {
          int l = n - m + (S_LEN - 1);
          SCc[((size_t)z * S_LEN + m) * S_LEN + n] =
              acc[i][j][r] + b2f(Tc[((size_t)z * S_LEN + m) * TSTRIDE + l]);
        }
      }
    }
}

__global__ __launch_bounds__(256) void k_softmax(const float* __restrict__ SCc,
                                                 short* __restrict__ PRc) {
  const int row = blockIdx.x;               // z*920 + q, z in [0,CHUNK)
  const float* src = SCc + (size_t)row * S_LEN;
  short* dst = PRc + (size_t)row * KPAD;
  const int tid = threadIdx.x, lane = tid & 63, wv = tid >> 6;
  float v[4];
#pragma unroll
  for (int i = 0; i < 4; ++i) {
    int k = i * 256 + tid;
    v[i] = (k < S_LEN) ? src[k] : -1e30f;
  }
  float mx = fmaxf(fmaxf(v[0], v[1]), fmaxf(v[2], v[3]));
  for (int off = 32; off; off >>= 1) mx = fmaxf(mx, __shfl_xor(mx, off));
  __shared__ float redm[4];
  __shared__ float reds[4];
  if (lane == 0) redm[wv] = mx;
  __syncthreads();
  mx = fmaxf(fmaxf(redm[0], redm[1]), fmaxf(redm[2], redm[3]));
  float e[4], s = 0.f;
#pragma unroll
  for (int i = 0; i < 4; ++i) { e[i] = __expf(v[i] - mx); s += e[i]; }
  for (int off = 32; off; off >>= 1) s += __shfl_xor(s, off);
  if (lane == 0) reds[wv] = s;
  __syncthreads();
  s = reds[0] + reds[1] + reds[2] + reds[3];
  float rs = 1.0f / s;
#pragma unroll
  for (int i = 0; i < 4; ++i) {
    int k = i * 256 + tid;
    if (k < KPAD) dst[k] = f2b(k < S_LEN ? e[i] * rs : 0.f);
  }
}

__global__ __launch_bounds__(256) void k_gemm_ctx(const short* __restrict__ PRc,
                                                  const short* __restrict__ Vt,
                                                  float* __restrict__ out, int c) {
  const int z = blockIdx.z;
  const int bh = c * CHUNK + z, b = bh >> 2, h = bh & 3;
  const int m0 = blockIdx.x * 128, n0 = blockIdx.y * 128;
  const short* A = PRc + (size_t)z * S_LEN * KPAD;
  const short* Bt = Vt + (size_t)bh * HD * KPAD;
  f32x4 acc[4][4];
  gemm_core(A, KPAD, S_LEN - 1, Bt, KPAD, HD - 1, KPAD, m0, n0, acc);
  const int tid = threadIdx.x, w = tid >> 6, lane = tid & 63;
  const int lr = lane & 15, lq = lane >> 4;
  const int wm = (w >> 1) * 64, wn = (w & 1) * 64;
#pragma unroll
  for (int i = 0; i < 4; ++i)
#pragma unroll
    for (int j = 0; j < 4; ++j) {
      int n = n0 + wn + j * 16 + lr;
#pragma unroll
      for (int r = 0; r < 4; ++r) {
        int m = m0 + wm + i * 16 + lq * 4 + r;
        if (m < S_LEN)
          out[((size_t)(b * S_LEN) + m) * DMODEL + h * HD + n] = acc[i][j][r];
      }
    }
}

// ---------------------------------------------------------------------------
extern "C" void kernel_launch(void* const* d_in, const int* in_sizes, int n_in,
                              void* d_out, int out_size, void* d_ws, size_t ws_size,
                              hipStream_t stream) {
  const float* hs = (const float*)d_in[0];
  const float* wq = (const float*)d_in[1];
  const float* wk = (const float*)d_in[2];
  const float* wv = (const float*)d_in[3];
  const float* de = (const float*)d_in[4];
  char* ws = (char*)d_ws;
  short* Xb = (short*)(ws + XB_OFF);
  short* Wt = (short*)(ws + WT_OFF);
  short* Tc = (short*)(ws + TC_OFF);
  float* SCc = (float*)(ws + SCC_OFF);
  short* PRc = (short*)(ws + PRC_OFF);
  short* Eb = (short*)(ws + EB_OFF);
  short* Vt = (short*)(ws + VT_OFF);
  short* out16 = (short*)d_out;

  k_cast<<<(MTOT * DMODEL / 4 + 255) / 256, 256, 0, stream>>>(hs, Xb, MTOT * DMODEL / 4);
  k_cast<<<(LREL * HD / 4 + 255) / 256, 256, 0, stream>>>(de, Eb, LREL * HD / 4);
  k_transpose_w<<<dim3(48, 48, 3), dim3(32, 8, 1), 0, stream>>>(wq, wk, wv, Wt);
  k_zero_vtpad<<<(NBH * HD * (KPAD - S_LEN) + 255) / 256, 256, 0, stream>>>(Vt);

  k_gemm_qkv<<<dim3(58, 12, 3), 256, 0, stream>>>(Xb, Wt, out16, Vt);

  for (int c = 0; c < NCHUNK; ++c) {
    k_gemm_T<<<dim3(8, 15, CHUNK), 256, 0, stream>>>(out16, Eb, Tc, c);
    k_gemm_scores<<<dim3(8, 8, CHUNK), 256, 0, stream>>>(out16, Tc, SCc, c);
    k_softmax<<<CHUNK * S_LEN, 256, 0, stream>>>(SCc, PRc);
    k_gemm_ctx<<<dim3(8, 3, CHUNK), 256, 0, stream>>>(PRc, Vt, (float*)d_out, c);
  }
}

// Round 3
// 616.274 us; speedup vs baseline: 1.1469x; 1.1469x over previous
//
#include <hip/hip_runtime.h>

#define S_LEN 920
#define DMODEL 1536
#define NH 4
#define HD 384
#define LREL 1839
#define BATCH 8
#define MTOT (BATCH * S_LEN)   // 7360
#define KPAD 960               // padded key-dim for PV gemm
#define TSTRIDE 1840           // padded L stride for T
#define NBH (BATCH * NH)       // 32

// ---- Q/K live inside d_out (shorts). Per 2-batch pair p, shorts
// [p*CHS, (p+1)*CHS) hold [Q(2p),K(2p),Q(2p+1),K(2p+1)]; chunk c's ctx output
// overwrites exactly its own batches' slabs AFTER scores consumed them.
#define CHS   5652480UL        // pair stride in shorts
#define BSLAB 2826240UL        // per-batch Q+K slab in shorts
#define KOFF  1413120UL        // K offset within batch slab (shorts)

// per-bh chunk buffer sizes (bytes)
#define T_BH   3385600UL       // 920*1840*2
#define SC_BH  3385600UL       // 920*920*4
#define PR_BH  1766400UL       // 920*960*2
#define CHBH   8537600UL       // sum
#define QKV_SCRATCH 36765696UL // Xb(22,609,920) + Wt(14,155,776)
#define EB_BYTES 1412352UL
#define VT_BYTES 23592960UL

typedef __attribute__((ext_vector_type(8))) short  s16x8;
typedef __attribute__((ext_vector_type(4))) short  s16x4;
typedef __attribute__((ext_vector_type(8))) __bf16 bf16x8;
typedef __attribute__((ext_vector_type(4))) float  f32x4;

__device__ __forceinline__ short f2b(float x) {
  unsigned u = __builtin_bit_cast(unsigned, x);
  unsigned r = (u + 0x7FFFu + ((u >> 16) & 1u)) >> 16;
  return (short)r;
}
__device__ __forceinline__ float b2f(short s) {
  unsigned u = ((unsigned)(unsigned short)s) << 16;
  return __builtin_bit_cast(float, u);
}

__device__ __forceinline__ void load_lds16(const short* g, short* lds) {
  __builtin_amdgcn_global_load_lds(
      (const __attribute__((address_space(1))) void*)g,
      (__attribute__((address_space(3))) void*)lds, 16, 0, 0);
}

__device__ __forceinline__ f32x4 mfma_bf16(s16x8 a, s16x8 b, f32x4 c) {
  return __builtin_amdgcn_mfma_f32_16x16x32_bf16(
      __builtin_bit_cast(bf16x8, a), __builtin_bit_cast(bf16x8, b), c, 0, 0, 0);
}

// ---------------------------------------------------------------------------
// 128x128 tile GEMM, C = A * B(NxK row-major)^T.  K multiple of 64.
// Staged row indices clamped to [0,mClamp]/[0,nClamp] (relative to base).
// acc[i][j][r] = C[m0+wm+i*16+(lane>>4)*4+r][n0+wn+j*16+(lane&15)]
// As/Bs: каждый 128*64 shorts (16 KB).
// ---------------------------------------------------------------------------
__device__ __forceinline__ void gemm_core(short* As, short* Bs,
                                          const short* __restrict__ A, int ldA, int mClamp,
                                          const short* __restrict__ B, int ldB, int nClamp,
                                          int K, int m0, int n0, f32x4 acc[4][4]) {
  const int tid  = threadIdx.x;
  const int w    = tid >> 6;
  const int lane = tid & 63;
  const int lrow = lane >> 3;
  const int lcol = (lane & 7) * 8;
  const int lr   = lane & 15;
  const int lq   = lane >> 4;
  const int wm   = (w >> 1) * 64;
  const int wn   = (w & 1) * 64;

  // hoisted per-thread staging addresses
  const short* pa[4];
  const short* pb[4];
  short* la[4];
  short* lb[4];
#pragma unroll
  for (int i = 0; i < 4; ++i) {
    int row = w * 32 + i * 8 + lrow;
    int ra = m0 + row; if (ra > mClamp) ra = mClamp;
    int rb = n0 + row; if (rb > nClamp) rb = nClamp;
    pa[i] = A + (size_t)ra * ldA + lcol;
    pb[i] = B + (size_t)rb * ldB + lcol;
    la[i] = &As[(w * 32 + i * 8) * 64];
    lb[i] = &Bs[(w * 32 + i * 8) * 64];
  }

#pragma unroll
  for (int i = 0; i < 4; ++i)
#pragma unroll
    for (int j = 0; j < 4; ++j) acc[i][j] = (f32x4){0.f, 0.f, 0.f, 0.f};

  for (int k0 = 0; k0 < K; k0 += 64) {
#pragma unroll
    for (int i = 0; i < 4; ++i) {
      load_lds16(pa[i] + k0, la[i]);
      load_lds16(pb[i] + k0, lb[i]);
    }
    __syncthreads();
#pragma unroll
    for (int kk = 0; kk < 2; ++kk) {
      s16x8 af[4], bf[4];
#pragma unroll
      for (int f = 0; f < 4; ++f)
        af[f] = *(const s16x8*)&As[(wm + f * 16 + lr) * 64 + kk * 32 + lq * 8];
#pragma unroll
      for (int f = 0; f < 4; ++f)
        bf[f] = *(const s16x8*)&Bs[(wn + f * 16 + lr) * 64 + kk * 32 + lq * 8];
#pragma unroll
      for (int i = 0; i < 4; ++i)
#pragma unroll
        for (int j = 0; j < 4; ++j)
          acc[i][j] = mfma_bf16(af[i], bf[j], acc[i][j]);
    }
    __syncthreads();
  }
}

// ---------------------------------------------------------------------------
__global__ void k_cast(const float* __restrict__ X, short* __restrict__ O, int n4) {
  int i = blockIdx.x * blockDim.x + threadIdx.x;
  if (i >= n4) return;
  float4 v = ((const float4*)X)[i];
  s16x4 o = {f2b(v.x), f2b(v.y), f2b(v.z), f2b(v.w)};
  *(s16x4*)&O[(size_t)i * 4] = o;
}

__global__ void k_transpose_w(const float* __restrict__ W0, const float* __restrict__ W1,
                              const float* __restrict__ W2, short* __restrict__ Wt) {
  const float* W = (blockIdx.z == 0) ? W0 : ((blockIdx.z == 1) ? W1 : W2);
  short* O = Wt + (size_t)blockIdx.z * DMODEL * DMODEL;
  __shared__ float t[32][33];
  int tx = threadIdx.x, ty = threadIdx.y;
  int n0 = blockIdx.x * 32, k0 = blockIdx.y * 32;
#pragma unroll
  for (int i = 0; i < 4; ++i)
    t[ty + i * 8][tx] = W[(size_t)(k0 + ty + i * 8) * DMODEL + n0 + tx];
  __syncthreads();
#pragma unroll
  for (int i = 0; i < 4; ++i)
    O[(size_t)(n0 + ty + i * 8) * DMODEL + k0 + tx] = f2b(t[tx][ty + i * 8]);
}

__global__ void k_zero_vtpad(short* __restrict__ Vt) {
  int idx = blockIdx.x * blockDim.x + threadIdx.x;
  if (idx >= NBH * HD * (KPAD - S_LEN)) return;
  int bhd = idx / (KPAD - S_LEN);
  int s = S_LEN + idx - bhd * (KPAD - S_LEN);
  Vt[(size_t)bhd * KPAD + s] = 0;
}

// ---------------------------------------------------------------------------
// QKV: grid (696, 1, 3).  Swizzle: bands of 29 m-tiles x all 12 n-tiles so a
// co-resident window shares one X band; X fetched ~once per z.
__global__ __launch_bounds__(256) void k_gemm_qkv(const short* __restrict__ Xb,
                                                  const short* __restrict__ Wt,
                                                  short* __restrict__ out16,
                                                  short* __restrict__ Vt) {
  __shared__ short smem[16896];   // gemm: 2x8192; z==2 epilogue: 128x132
  const int z = blockIdx.z;
  int t = blockIdx.x;
  int band = t / 348;                 // 12*29
  int rr = t - band * 348;
  int n_idx = rr / 29;
  int m_idx = band * 29 + (rr - n_idx * 29);
  const int m0 = m_idx * 128, n0 = n_idx * 128;

  f32x4 acc[4][4];
  gemm_core(smem, smem + 8192, Xb, DMODEL, MTOT - 1,
            Wt + (size_t)z * DMODEL * DMODEL, DMODEL, DMODEL - 1,
            DMODEL, m0, n0, acc);

  const int tid = threadIdx.x, w = tid >> 6, lane = tid & 63;
  const int lr = lane & 15, lq = lane >> 4;
  const int wm = (w >> 1) * 64, wn = (w & 1) * 64;

  if (z == 2) {
    // transpose tile through LDS (stride 132 shorts: conflict-free quads),
    // then coalesced row-stores into Vt.
    short* T16 = smem;
#pragma unroll
    for (int i = 0; i < 4; ++i)
#pragma unroll
      for (int j = 0; j < 4; ++j) {
        int n_local = wn + j * 16 + lr;
#pragma unroll
        for (int r = 0; r < 4; ++r) {
          int m_local = wm + i * 16 + lq * 4 + r;
          T16[n_local * 132 + m_local] = f2b(acc[i][j][r]);
        }
      }
    __syncthreads();
    const int m_local = tid & 127, half = tid >> 7;
    const int m = m0 + m_local;
    if (m < MTOT) {
      const int b = m / S_LEN, s = m - b * S_LEN;
      for (int p = 0; p < 64; ++p) {
        int n_local = p * 2 + half;
        int n = n0 + n_local;
        int h = n / HD, d = n - h * HD;
        Vt[(((size_t)(b * NH + h)) * HD + d) * KPAD + s] = T16[n_local * 132 + m_local];
      }
    }
  } else {
    const float inv = 0.05103103630798287f;  // 1/sqrt(384)
#pragma unroll
    for (int i = 0; i < 4; ++i)
#pragma unroll
      for (int j = 0; j < 4; ++j) {
        int n = n0 + wn + j * 16 + lr;
#pragma unroll
        for (int r = 0; r < 4; ++r) {
          int m = m0 + wm + i * 16 + lq * 4 + r;
          if (m >= MTOT) continue;
          float v = acc[i][j][r];
          int b = m / S_LEN, s = m - b * S_LEN;
          short* dst = out16 + (size_t)(b >> 1) * CHS + (size_t)(b & 1) * BSLAB +
                       (z == 1 ? KOFF : 0UL);
          dst[(size_t)s * DMODEL + n] = f2b(z == 0 ? v * inv : v);
        }
      }
  }
}

// T = Q @ E^T : grid (120, 1, CH); n innermost so each Q tile is read once.
__global__ __launch_bounds__(256) void k_gemm_T(const short* __restrict__ out16,
                                                const short* __restrict__ Eb,
                                                short* __restrict__ Tc, int bh0) {
  __shared__ short smem[16384];
  const int z = blockIdx.z;
  const int bh = bh0 + z, b = bh >> 2, h = bh & 3;
  int t = blockIdx.x;
  int m_idx = t / 15, n_idx = t - m_idx * 15;
  const int m0 = m_idx * 128, n0 = n_idx * 128;
  const short* A = out16 + (size_t)(b >> 1) * CHS + (size_t)(b & 1) * BSLAB + h * HD;
  f32x4 acc[4][4];
  gemm_core(smem, smem + 8192, A, DMODEL, S_LEN - 1, Eb, HD, LREL - 1, HD, m0, n0, acc);
  const int tid = threadIdx.x, w = tid >> 6, lane = tid & 63;
  const int lr = lane & 15, lq = lane >> 4;
  const int wm = (w >> 1) * 64, wn = (w & 1) * 64;
#pragma unroll
  for (int i = 0; i < 4; ++i)
#pragma unroll
    for (int j = 0; j < 4; ++j) {
      int n = n0 + wn + j * 16 + lr;
#pragma unroll
      for (int r = 0; r < 4; ++r) {
        int m = m0 + wm + i * 16 + lq * 4 + r;
        if (m < S_LEN && n < LREL)
          Tc[((size_t)z * S_LEN + m) * TSTRIDE + n] = f2b(acc[i][j][r]);
      }
    }
}

__global__ __launch_bounds__(256) void k_gemm_scores(const short* __restrict__ out16,
                                                     const short* __restrict__ Tc,
                                                     float* __restrict__ SCc, int bh0) {
  __shared__ short smem[16384];
  const int z = blockIdx.z;
  const int bh = bh0 + z, b = bh >> 2, h = bh & 3;
  const int m0 = blockIdx.x * 128, n0 = blockIdx.y * 128;
  const short* Qp = out16 + (size_t)(b >> 1) * CHS + (size_t)(b & 1) * BSLAB + h * HD;
  const short* Kp = Qp + KOFF;
  f32x4 acc[4][4];
  gemm_core(smem, smem + 8192, Qp, DMODEL, S_LEN - 1, Kp, DMODEL, S_LEN - 1, HD, m0, n0, acc);
  const int tid = threadIdx.x, w = tid >> 6, lane = tid & 63;
  const int lr = lane & 15, lq = lane >> 4;
  const int wm = (w >> 1) * 64, wn = (w & 1) * 64;
#pragma unroll
  for (int i = 0; i < 4; ++i)
#pragma unroll
    for (int j = 0; j < 4; ++j) {
      int n = n0 + wn + j * 16 + lr;
#pragma unroll
      for (int r = 0; r < 4; ++r) {
        int m = m0 + wm + i * 16 + lq * 4 + r;
        if (m < S_LEN && n < S_LEN) {
          int l = n - m + (S_LEN - 1);
          SCc[((size_t)z * S_LEN + m) * S_LEN + n] =
              acc[i][j][r] + b2f(Tc[((size_t)z * S_LEN + m) * TSTRIDE + l]);
        }
      }
    }
}

__global__ __launch_bounds__(256) void k_softmax(const float* __restrict__ SCc,
                                                 short* __restrict__ PRc) {
  const int row = blockIdx.x;               // z*920 + q
  const float* src = SCc + (size_t)row * S_LEN;
  short* dst = PRc + (size_t)row * KPAD;
  const int tid = threadIdx.x, lane = tid & 63, wv = tid >> 6;
  float v[4];
#pragma unroll
  for (int i = 0; i < 4; ++i) {
    int k = i * 256 + tid;
    v[i] = (k < S_LEN) ? src[k] : -1e30f;
  }
  float mx = fmaxf(fmaxf(v[0], v[1]), fmaxf(v[2], v[3]));
  for (int off = 32; off; off >>= 1) mx = fmaxf(mx, __shfl_xor(mx, off));
  __shared__ float redm[4];
  __shared__ float reds[4];
  if (lane == 0) redm[wv] = mx;
  __syncthreads();
  mx = fmaxf(fmaxf(redm[0], redm[1]), fmaxf(redm[2], redm[3]));
  float e[4], s = 0.f;
#pragma unroll
  for (int i = 0; i < 4; ++i) { e[i] = __expf(v[i] - mx); s += e[i]; }
  for (int off = 32; off; off >>= 1) s += __shfl_xor(s, off);
  if (lane == 0) reds[wv] = s;
  __syncthreads();
  s = reds[0] + reds[1] + reds[2] + reds[3];
  float rs = 1.0f / s;
#pragma unroll
  for (int i = 0; i < 4; ++i) {
    int k = i * 256 + tid;
    if (k < KPAD) dst[k] = f2b(k < S_LEN ? e[i] * rs : 0.f);
  }
}

__global__ __launch_bounds__(256) void k_gemm_ctx(const short* __restrict__ PRc,
                                                  const short* __restrict__ Vt,
                                                  float* __restrict__ out, int bh0) {
  __shared__ short smem[16384];
  const int z = blockIdx.z;
  const int bh = bh0 + z, b = bh >> 2, h = bh & 3;
  const int m0 = blockIdx.x * 128, n0 = blockIdx.y * 128;
  const short* A = PRc + (size_t)z * S_LEN * KPAD;
  const short* Bt = Vt + (size_t)bh * HD * KPAD;
  f32x4 acc[4][4];
  gemm_core(smem, smem + 8192, A, KPAD, S_LEN - 1, Bt, KPAD, HD - 1, KPAD, m0, n0, acc);
  const int tid = threadIdx.x, w = tid >> 6, lane = tid & 63;
  const int lr = lane & 15, lq = lane >> 4;
  const int wm = (w >> 1) * 64, wn = (w & 1) * 64;
#pragma unroll
  for (int i = 0; i < 4; ++i)
#pragma unroll
    for (int j = 0; j < 4; ++j) {
      int n = n0 + wn + j * 16 + lr;
#pragma unroll
      for (int r = 0; r < 4; ++r) {
        int m = m0 + wm + i * 16 + lq * 4 + r;
        if (m < S_LEN)
          out[((size_t)(b * S_LEN) + m) * DMODEL + h * HD + n] = acc[i][j][r];
      }
    }
}

// ---------------------------------------------------------------------------
extern "C" void kernel_launch(void* const* d_in, const int* in_sizes, int n_in,
                              void* d_out, int out_size, void* d_ws, size_t ws_size,
                              hipStream_t stream) {
  const float* hs = (const float*)d_in[0];
  const float* wq = (const float*)d_in[1];
  const float* wk = (const float*)d_in[2];
  const float* wv = (const float*)d_in[3];
  const float* de = (const float*)d_in[4];
  char* ws = (char*)d_ws;

  // chunk size selected from ws_size (constant per process -> graph-safe)
  int CH;
  if      (ws_size >= 32 * CHBH + EB_BYTES + VT_BYTES) CH = 32;   // 298,208,512
  else if (ws_size >= 16 * CHBH + EB_BYTES + VT_BYTES) CH = 16;   // 161,606,912
  else                                                  CH = 8;   //  93,306,112
  size_t chunk_bytes = (size_t)CH * CHBH;
  size_t fixed_base = chunk_bytes > QKV_SCRATCH ? chunk_bytes : QKV_SCRATCH;

  short* Xb  = (short*)(ws + 0);
  short* Wt  = (short*)(ws + 22609920UL);
  short* Tc  = (short*)(ws + 0);                         // aliases Xb/Wt (dead)
  float* SCc = (float*)(ws + (size_t)CH * T_BH);
  short* PRc = (short*)(ws + (size_t)CH * (T_BH + SC_BH));
  short* Eb  = (short*)(ws + fixed_base);
  short* Vt  = (short*)(ws + fixed_base + EB_BYTES);
  short* out16 = (short*)d_out;

  k_cast<<<(MTOT * DMODEL / 4 + 255) / 256, 256, 0, stream>>>(hs, Xb, MTOT * DMODEL / 4);
  k_cast<<<(LREL * HD / 4 + 255) / 256, 256, 0, stream>>>(de, Eb, LREL * HD / 4);
  k_transpose_w<<<dim3(48, 48, 3), dim3(32, 8, 1), 0, stream>>>(wq, wk, wv, Wt);
  k_zero_vtpad<<<(NBH * HD * (KPAD - S_LEN) + 255) / 256, 256, 0, stream>>>(Vt);

  k_gemm_qkv<<<dim3(696, 1, 3), 256, 0, stream>>>(Xb, Wt, out16, Vt);

  int NC = 32 / CH;
  for (int c = 0; c < NC; ++c) {
    int bh0 = c * CH;
    k_gemm_T<<<dim3(120, 1, CH), 256, 0, stream>>>(out16, Eb, Tc, bh0);
    k_gemm_scores<<<dim3(8, 8, CH), 256, 0, stream>>>(out16, Tc, SCc, bh0);
    k_softmax<<<CH * S_LEN, 256, 0, stream>>>(SCc, PRc);
    k_gemm_ctx<<<dim3(8, 3, CH), 256, 0, stream>>>(PRc, Vt, (float*)d_out, bh0);
  }
}

// Round 4
// 572.741 us; speedup vs baseline: 1.2340x; 1.0760x over previous
//
#include <hip/hip_runtime.h>

#define S_LEN 920
#define DMODEL 1536
#define NH 4
#define HD 384
#define LREL 1839
#define BATCH 8
#define MTOT (BATCH * S_LEN)   // 7360
#define KPAD 960               // padded key-dim for PV gemm
#define TSTRIDE 1840           // padded L stride for T
#define NBH (BATCH * NH)       // 32

// ---- Q/K live inside d_out (shorts). Per 2-batch pair p, shorts
// [p*CHS, (p+1)*CHS) hold [Q(2p),K(2p),Q(2p+1),K(2p+1)]; chunk c's ctx output
// overwrites exactly its own batches' slabs AFTER scores consumed them.
#define CHS   5652480UL        // pair stride in shorts
#define BSLAB 2826240UL        // per-batch Q+K slab in shorts
#define KOFF  1413120UL        // K offset within batch slab (shorts)

// per-bh chunk buffer sizes (bytes)
#define T_BH   3385600UL       // 920*1840*2
#define SC_BH  3385600UL       // 920*920*4
#define PR_BH  1766400UL       // 920*960*2
#define CHBH   8537600UL       // sum
#define QKV_SCRATCH 36765696UL // Xb(22,609,920) + Wt(14,155,776)
#define EB_BYTES 1412352UL
#define VT_BYTES 23592960UL

typedef __attribute__((ext_vector_type(8))) short  s16x8;
typedef __attribute__((ext_vector_type(4))) short  s16x4;
typedef __attribute__((ext_vector_type(8))) __bf16 bf16x8;
typedef __attribute__((ext_vector_type(4))) float  f32x4;

__device__ __forceinline__ short f2b(float x) {
  unsigned u = __builtin_bit_cast(unsigned, x);
  unsigned r = (u + 0x7FFFu + ((u >> 16) & 1u)) >> 16;
  return (short)r;
}
__device__ __forceinline__ float b2f(short s) {
  unsigned u = ((unsigned)(unsigned short)s) << 16;
  return __builtin_bit_cast(float, u);
}

__device__ __forceinline__ void load_lds16(const short* g, short* lds) {
  __builtin_amdgcn_global_load_lds(
      (const __attribute__((address_space(1))) void*)g,
      (__attribute__((address_space(3))) void*)lds, 16, 0, 0);
}

__device__ __forceinline__ f32x4 mfma_bf16(s16x8 a, s16x8 b, f32x4 c) {
  return __builtin_amdgcn_mfma_f32_16x16x32_bf16(
      __builtin_bit_cast(bf16x8, a), __builtin_bit_cast(bf16x8, b), c, 0, 0, 0);
}

// ---------------------------------------------------------------------------
// 128x128 tile GEMM, C = A * B(NxK row-major)^T.  K multiple of 64.
// acc[i][j][r] = C[m0+wm+i*16+(lane>>4)*4+r][n0+wn+j*16+(lane&15)]
// As/Bs: 128*64 shorts each.
// ---------------------------------------------------------------------------
__device__ __forceinline__ void gemm_core(short* As, short* Bs,
                                          const short* __restrict__ A, int ldA, int mClamp,
                                          const short* __restrict__ B, int ldB, int nClamp,
                                          int K, int m0, int n0, f32x4 acc[4][4]) {
  const int tid  = threadIdx.x;
  const int w    = tid >> 6;
  const int lane = tid & 63;
  const int lrow = lane >> 3;
  const int lcol = (lane & 7) * 8;
  const int lr   = lane & 15;
  const int lq   = lane >> 4;
  const int wm   = (w >> 1) * 64;
  const int wn   = (w & 1) * 64;

  const short* pa[4];
  const short* pb[4];
  short* la[4];
  short* lb[4];
#pragma unroll
  for (int i = 0; i < 4; ++i) {
    int row = w * 32 + i * 8 + lrow;
    int ra = m0 + row; if (ra > mClamp) ra = mClamp;
    int rb = n0 + row; if (rb > nClamp) rb = nClamp;
    pa[i] = A + (size_t)ra * ldA + lcol;
    pb[i] = B + (size_t)rb * ldB + lcol;
    la[i] = &As[(w * 32 + i * 8) * 64];
    lb[i] = &Bs[(w * 32 + i * 8) * 64];
  }

#pragma unroll
  for (int i = 0; i < 4; ++i)
#pragma unroll
    for (int j = 0; j < 4; ++j) acc[i][j] = (f32x4){0.f, 0.f, 0.f, 0.f};

  for (int k0 = 0; k0 < K; k0 += 64) {
#pragma unroll
    for (int i = 0; i < 4; ++i) {
      load_lds16(pa[i] + k0, la[i]);
      load_lds16(pb[i] + k0, lb[i]);
    }
    __syncthreads();
#pragma unroll
    for (int kk = 0; kk < 2; ++kk) {
      s16x8 af[4], bf[4];
#pragma unroll
      for (int f = 0; f < 4; ++f)
        af[f] = *(const s16x8*)&As[(wm + f * 16 + lr) * 64 + kk * 32 + lq * 8];
#pragma unroll
      for (int f = 0; f < 4; ++f)
        bf[f] = *(const s16x8*)&Bs[(wn + f * 16 + lr) * 64 + kk * 32 + lq * 8];
#pragma unroll
      for (int i = 0; i < 4; ++i)
#pragma unroll
        for (int j = 0; j < 4; ++j)
          acc[i][j] = mfma_bf16(af[i], bf[j], acc[i][j]);
    }
    __syncthreads();
  }
}

// ---------------------------------------------------------------------------
// 128x256 tile GEMM.  As: 128*64 shorts, Bs: 256*64 shorts.
// acc[i][j][r] = C[m0+(w>>1)*64+i*16+(lane>>4)*4+r][n0+(w&1)*128+j*16+(lane&15)]
// ---------------------------------------------------------------------------
__device__ __forceinline__ void gemm_core256(short* As, short* Bs,
                                             const short* __restrict__ A, int ldA, int mClamp,
                                             const short* __restrict__ B, int ldB, int nClamp,
                                             int K, int m0, int n0, f32x4 acc[4][8]) {
  const int tid  = threadIdx.x;
  const int w    = tid >> 6;
  const int lane = tid & 63;
  const int lrow = lane >> 3;
  const int lcol = (lane & 7) * 8;
  const int lr   = lane & 15;
  const int lq   = lane >> 4;
  const int wm   = (w >> 1) * 64;
  const int wn   = (w & 1) * 128;

  const short* pa[4];
  short* la[4];
  const short* pb[8];
  short* lb[8];
#pragma unroll
  for (int i = 0; i < 4; ++i) {
    int row = w * 32 + i * 8 + lrow;
    int ra = m0 + row; if (ra > mClamp) ra = mClamp;
    pa[i] = A + (size_t)ra * ldA + lcol;
    la[i] = &As[(w * 32 + i * 8) * 64];
  }
#pragma unroll
  for (int i = 0; i < 8; ++i) {
    int row = w * 64 + i * 8 + lrow;
    int rb = n0 + row; if (rb > nClamp) rb = nClamp;
    pb[i] = B + (size_t)rb * ldB + lcol;
    lb[i] = &Bs[(w * 64 + i * 8) * 64];
  }

#pragma unroll
  for (int i = 0; i < 4; ++i)
#pragma unroll
    for (int j = 0; j < 8; ++j) acc[i][j] = (f32x4){0.f, 0.f, 0.f, 0.f};

  for (int k0 = 0; k0 < K; k0 += 64) {
#pragma unroll
    for (int i = 0; i < 4; ++i) load_lds16(pa[i] + k0, la[i]);
#pragma unroll
    for (int i = 0; i < 8; ++i) load_lds16(pb[i] + k0, lb[i]);
    __syncthreads();
#pragma unroll
    for (int kk = 0; kk < 2; ++kk) {
      s16x8 af[4], bf[8];
#pragma unroll
      for (int f = 0; f < 4; ++f)
        af[f] = *(const s16x8*)&As[(wm + f * 16 + lr) * 64 + kk * 32 + lq * 8];
#pragma unroll
      for (int f = 0; f < 8; ++f)
        bf[f] = *(const s16x8*)&Bs[(wn + f * 16 + lr) * 64 + kk * 32 + lq * 8];
#pragma unroll
      for (int i = 0; i < 4; ++i)
#pragma unroll
        for (int j = 0; j < 8; ++j)
          acc[i][j] = mfma_bf16(af[i], bf[j], acc[i][j]);
    }
    __syncthreads();
  }
}

// ---------------------------------------------------------------------------
__global__ void k_cast(const float* __restrict__ X, short* __restrict__ O, int n4) {
  int i = blockIdx.x * blockDim.x + threadIdx.x;
  if (i >= n4) return;
  float4 v = ((const float4*)X)[i];
  s16x4 o = {f2b(v.x), f2b(v.y), f2b(v.z), f2b(v.w)};
  *(s16x4*)&O[(size_t)i * 4] = o;
}

__global__ void k_transpose_w(const float* __restrict__ W0, const float* __restrict__ W1,
                              const float* __restrict__ W2, short* __restrict__ Wt) {
  const float* W = (blockIdx.z == 0) ? W0 : ((blockIdx.z == 1) ? W1 : W2);
  short* O = Wt + (size_t)blockIdx.z * DMODEL * DMODEL;
  __shared__ float t[32][33];
  int tx = threadIdx.x, ty = threadIdx.y;
  int n0 = blockIdx.x * 32, k0 = blockIdx.y * 32;
#pragma unroll
  for (int i = 0; i < 4; ++i)
    t[ty + i * 8][tx] = W[(size_t)(k0 + ty + i * 8) * DMODEL + n0 + tx];
  __syncthreads();
#pragma unroll
  for (int i = 0; i < 4; ++i)
    O[(size_t)(n0 + ty + i * 8) * DMODEL + k0 + tx] = f2b(t[tx][ty + i * 8]);
}

__global__ void k_zero_vtpad(short* __restrict__ Vt) {
  int idx = blockIdx.x * blockDim.x + threadIdx.x;
  if (idx >= NBH * HD * (KPAD - S_LEN)) return;
  int bhd = idx / (KPAD - S_LEN);
  int s = S_LEN + idx - bhd * (KPAD - S_LEN);
  Vt[(size_t)bhd * KPAD + s] = 0;
}

// ---------------------------------------------------------------------------
// QKV: 128x256 tiles.  Grid (348,1,3): per z, 58 m-tiles x 6 n-tiles, banded
// (2 bands of 29 m x 6 n).
__global__ __launch_bounds__(256, 2) void k_gemm_qkv(const short* __restrict__ Xb,
                                                     const short* __restrict__ Wt,
                                                     short* __restrict__ out16,
                                                     short* __restrict__ Vt) {
  __shared__ short smem[24576];   // As 8192 + Bs 16384; epilogue reuses 16896
  const int z = blockIdx.z;
  int t = blockIdx.x;
  int band = t / 174;                 // 6*29
  int rr = t - band * 174;
  int n_idx = rr / 29;
  int m_idx = band * 29 + (rr - n_idx * 29);
  const int m0 = m_idx * 128, n0 = n_idx * 256;

  f32x4 acc[4][8];
  gemm_core256(smem, smem + 8192, Xb, DMODEL, MTOT - 1,
               Wt + (size_t)z * DMODEL * DMODEL, DMODEL, DMODEL - 1,
               DMODEL, m0, n0, acc);

  const int tid = threadIdx.x, w = tid >> 6, lane = tid & 63;
  const int lr = lane & 15, lq = lane >> 4;
  const int wm = (w >> 1) * 64, wn = (w & 1) * 128;

  if (z == 2) {
    // transpose each 128-wide n-half through LDS (stride 132), store Vt rows.
    short* T16 = smem;
    const int m_local_s = tid & 127, h2 = tid >> 7;
    for (int half = 0; half < 2; ++half) {
      if ((w & 1) == half) {
#pragma unroll
        for (int i = 0; i < 4; ++i)
#pragma unroll
          for (int j = 0; j < 8; ++j) {
            int nl = j * 16 + lr;            // [0,128)
#pragma unroll
            for (int r = 0; r < 4; ++r)
              T16[nl * 132 + wm + i * 16 + lq * 4 + r] = f2b(acc[i][j][r]);
          }
      }
      __syncthreads();
      const int m = m0 + m_local_s;
      if (m < MTOT) {
        const int b = m / S_LEN, s = m - b * S_LEN;
        for (int p = 0; p < 64; ++p) {
          int nl = p * 2 + h2;
          int n = n0 + half * 128 + nl;
          int h = n / HD, d = n - h * HD;
          Vt[(((size_t)(b * NH + h)) * HD + d) * KPAD + s] = T16[nl * 132 + m_local_s];
        }
      }
      __syncthreads();
    }
  } else {
    const float inv = 0.05103103630798287f;  // 1/sqrt(384)
#pragma unroll
    for (int i = 0; i < 4; ++i)
#pragma unroll
      for (int j = 0; j < 8; ++j) {
        int n = n0 + wn + j * 16 + lr;
#pragma unroll
        for (int r = 0; r < 4; ++r) {
          int m = m0 + wm + i * 16 + lq * 4 + r;
          if (m >= MTOT) continue;
          float v = acc[i][j][r];
          int b = m / S_LEN, s = m - b * S_LEN;
          short* dst = out16 + (size_t)(b >> 1) * CHS + (size_t)(b & 1) * BSLAB +
                       (z == 1 ? KOFF : 0UL);
          dst[(size_t)s * DMODEL + n] = f2b(z == 0 ? v * inv : v);
        }
      }
  }
}

// T = Q @ E^T, banded: only tiles (i,j) with 6 <= i+j <= 14 are ever read by
// scores (l = n-m+919, n<920).  71 tiles instead of 120.  Grid (71,1,CH).
__global__ __launch_bounds__(256) void k_gemm_T(const short* __restrict__ out16,
                                                const short* __restrict__ Eb,
                                                short* __restrict__ Tc, int bh0) {
  __shared__ short smem[16384];
  const int z = blockIdx.z;
  const int bh = bh0 + z, b = bh >> 2, h = bh & 3;
  int t = blockIdx.x;
  int i_idx, j_idx;
  if (t < 7) { i_idx = t; j_idx = 6 - t; }
  else { int u = t - 7; int s = 7 + (u >> 3); i_idx = u & 7; j_idx = s - i_idx; }
  const int m0 = i_idx * 128, n0 = j_idx * 128;
  const short* A = out16 + (size_t)(b >> 1) * CHS + (size_t)(b & 1) * BSLAB + h * HD;
  f32x4 acc[4][4];
  gemm_core(smem, smem + 8192, A, DMODEL, S_LEN - 1, Eb, HD, LREL - 1, HD, m0, n0, acc);
  const int tid = threadIdx.x, w = tid >> 6, lane = tid & 63;
  const int lr = lane & 15, lq = lane >> 4;
  const int wm = (w >> 1) * 64, wn = (w & 1) * 64;
#pragma unroll
  for (int i = 0; i < 4; ++i)
#pragma unroll
    for (int j = 0; j < 4; ++j) {
      int n = n0 + wn + j * 16 + lr;
#pragma unroll
      for (int r = 0; r < 4; ++r) {
        int m = m0 + wm + i * 16 + lq * 4 + r;
        if (m < S_LEN && n < LREL)
          Tc[((size_t)z * S_LEN + m) * TSTRIDE + n] = f2b(acc[i][j][r]);
      }
    }
}

// scores: 128x256 tiles.  Grid (8,4,CH).
__global__ __launch_bounds__(256, 2) void k_gemm_scores(const short* __restrict__ out16,
                                                        const short* __restrict__ Tc,
                                                        float* __restrict__ SCc, int bh0) {
  __shared__ short smem[24576];
  const int z = blockIdx.z;
  const int bh = bh0 + z, b = bh >> 2, h = bh & 3;
  const int m0 = blockIdx.x * 128, n0 = blockIdx.y * 256;
  const short* Qp = out16 + (size_t)(b >> 1) * CHS + (size_t)(b & 1) * BSLAB + h * HD;
  const short* Kp = Qp + KOFF;
  f32x4 acc[4][8];
  gemm_core256(smem, smem + 8192, Qp, DMODEL, S_LEN - 1, Kp, DMODEL, S_LEN - 1,
               HD, m0, n0, acc);
  const int tid = threadIdx.x, w = tid >> 6, lane = tid & 63;
  const int lr = lane & 15, lq = lane >> 4;
  const int wm = (w >> 1) * 64, wn = (w & 1) * 128;
#pragma unroll
  for (int i = 0; i < 4; ++i)
#pragma unroll
    for (int j = 0; j < 8; ++j) {
      int n = n0 + wn + j * 16 + lr;
#pragma unroll
      for (int r = 0; r < 4; ++r) {
        int m = m0 + wm + i * 16 + lq * 4 + r;
        if (m < S_LEN && n < S_LEN) {
          int l = n - m + (S_LEN - 1);
          SCc[((size_t)z * S_LEN + m) * S_LEN + n] =
              acc[i][j][r] + b2f(Tc[((size_t)z * S_LEN + m) * TSTRIDE + l]);
        }
      }
    }
}

__global__ __launch_bounds__(256) void k_softmax(const float* __restrict__ SCc,
                                                 short* __restrict__ PRc) {
  const int row = blockIdx.x;               // z*920 + q
  const float* src = SCc + (size_t)row * S_LEN;
  short* dst = PRc + (size_t)row * KPAD;
  const int tid = threadIdx.x, lane = tid & 63, wv = tid >> 6;
  float v[4];
#pragma unroll
  for (int i = 0; i < 4; ++i) {
    int k = i * 256 + tid;
    v[i] = (k < S_LEN) ? src[k] : -1e30f;
  }
  float mx = fmaxf(fmaxf(v[0], v[1]), fmaxf(v[2], v[3]));
  for (int off = 32; off; off >>= 1) mx = fmaxf(mx, __shfl_xor(mx, off));
  __shared__ float redm[4];
  __shared__ float reds[4];
  if (lane == 0) redm[wv] = mx;
  __syncthreads();
  mx = fmaxf(fmaxf(redm[0], redm[1]), fmaxf(redm[2], redm[3]));
  float e[4], s = 0.f;
#pragma unroll
  for (int i = 0; i < 4; ++i) { e[i] = __expf(v[i] - mx); s += e[i]; }
  for (int off = 32; off; off >>= 1) s += __shfl_xor(s, off);
  if (lane == 0) reds[wv] = s;
  __syncthreads();
  s = reds[0] + reds[1] + reds[2] + reds[3];
  float rs = 1.0f / s;
#pragma unroll
  for (int i = 0; i < 4; ++i) {
    int k = i * 256 + tid;
    if (k < KPAD) dst[k] = f2b(k < S_LEN ? e[i] * rs : 0.f);
  }
}

__global__ __launch_bounds__(256) void k_gemm_ctx(const short* __restrict__ PRc,
                                                  const short* __restrict__ Vt,
                                                  float* __restrict__ out, int bh0) {
  __shared__ short smem[16384];
  const int z = blockIdx.z;
  const int bh = bh0 + z, b = bh >> 2, h = bh & 3;
  const int m0 = blockIdx.x * 128, n0 = blockIdx.y * 128;
  const short* A = PRc + (size_t)z * S_LEN * KPAD;
  const short* Bt = Vt + (size_t)bh * HD * KPAD;
  f32x4 acc[4][4];
  gemm_core(smem, smem + 8192, A, KPAD, S_LEN - 1, Bt, KPAD, HD - 1, KPAD, m0, n0, acc);
  const int tid = threadIdx.x, w = tid >> 6, lane = tid & 63;
  const int lr = lane & 15, lq = lane >> 4;
  const int wm = (w >> 1) * 64, wn = (w & 1) * 64;
#pragma unroll
  for (int i = 0; i < 4; ++i)
#pragma unroll
    for (int j = 0; j < 4; ++j) {
      int n = n0 + wn + j * 16 + lr;
#pragma unroll
      for (int r = 0; r < 4; ++r) {
        int m = m0 + wm + i * 16 + lq * 4 + r;
        if (m < S_LEN)
          out[((size_t)(b * S_LEN) + m) * DMODEL + h * HD + n] = acc[i][j][r];
      }
    }
}

// ---------------------------------------------------------------------------
extern "C" void kernel_launch(void* const* d_in, const int* in_sizes, int n_in,
                              void* d_out, int out_size, void* d_ws, size_t ws_size,
                              hipStream_t stream) {
  const float* hs = (const float*)d_in[0];
  const float* wq = (const float*)d_in[1];
  const float* wk = (const float*)d_in[2];
  const float* wv = (const float*)d_in[3];
  const float* de = (const float*)d_in[4];
  char* ws = (char*)d_ws;

  int CH;
  if      (ws_size >= 32 * CHBH + EB_BYTES + VT_BYTES) CH = 32;
  else if (ws_size >= 16 * CHBH + EB_BYTES + VT_BYTES) CH = 16;
  else                                                  CH = 8;
  size_t chunk_bytes = (size_t)CH * CHBH;
  size_t fixed_base = chunk_bytes > QKV_SCRATCH ? chunk_bytes : QKV_SCRATCH;

  short* Xb  = (short*)(ws + 0);
  short* Wt  = (short*)(ws + 22609920UL);
  short* Tc  = (short*)(ws + 0);                         // aliases Xb/Wt (dead)
  float* SCc = (float*)(ws + (size_t)CH * T_BH);
  short* PRc = (short*)(ws + (size_t)CH * (T_BH + SC_BH));
  short* Eb  = (short*)(ws + fixed_base);
  short* Vt  = (short*)(ws + fixed_base + EB_BYTES);
  short* out16 = (short*)d_out;

  k_cast<<<(MTOT * DMODEL / 4 + 255) / 256, 256, 0, stream>>>(hs, Xb, MTOT * DMODEL / 4);
  k_cast<<<(LREL * HD / 4 + 255) / 256, 256, 0, stream>>>(de, Eb, LREL * HD / 4);
  k_transpose_w<<<dim3(48, 48, 3), dim3(32, 8, 1), 0, stream>>>(wq, wk, wv, Wt);
  k_zero_vtpad<<<(NBH * HD * (KPAD - S_LEN) + 255) / 256, 256, 0, stream>>>(Vt);

  k_gemm_qkv<<<dim3(348, 1, 3), 256, 0, stream>>>(Xb, Wt, out16, Vt);

  int NC = 32 / CH;
  for (int c = 0; c < NC; ++c) {
    int bh0 = c * CH;
    k_gemm_T<<<dim3(71, 1, CH), 256, 0, stream>>>(out16, Eb, Tc, bh0);
    k_gemm_scores<<<dim3(8, 4, CH), 256, 0, stream>>>(out16, Tc, SCc, bh0);
    k_softmax<<<CH * S_LEN, 256, 0, stream>>>(SCc, PRc);
    k_gemm_ctx<<<dim3(8, 3, CH), 256, 0, stream>>>(PRc, Vt, (float*)d_out, bh0);
  }
}

// Round 5
// 553.248 us; speedup vs baseline: 1.2775x; 1.0352x over previous
//
#include <hip/hip_runtime.h>

#define S_LEN 920
#define DMODEL 1536
#define NH 4
#define HD 384
#define LREL 1839
#define BATCH 8
#define MTOT (BATCH * S_LEN)   // 7360
#define KPAD 960               // padded key-dim for PV gemm (Vt cols, PR cols)
#define PRLD 1840              // PR row stride in shorts (= SC row bytes/2)
#define NBH (BATCH * NH)       // 32

// ---- Q/K live inside d_out (shorts). Per 2-batch pair p, shorts
// [p*CHS, (p+1)*CHS) hold [Q(2p),K(2p),Q(2p+1),K(2p+1)]; chunk c's ctx output
// overwrites exactly its own batches' slabs AFTER scores consumed them.
#define CHS   5652480UL        // pair stride in shorts
#define BSLAB 2826240UL        // per-batch Q+K slab in shorts
#define KOFF  1413120UL        // K offset within batch slab (shorts)

// per-bh chunk buffer sizes (bytes)
#define TP_BH   1692800UL      // packed T: 920*920*2
#define SCPR_BH 3385600UL      // SC fp32 920*920*4; softmax overwrites in-place
                               // with PR bf16 rows (stride 1840 shorts, 960 used)
#define CHBH    (TP_BH + SCPR_BH)   // 5,078,400
#define QKV_SCRATCH 36765696UL // Xb(22,609,920) + Wt(14,155,776)
#define EB_BYTES 1412352UL
#define VT_BYTES 23592960UL

typedef __attribute__((ext_vector_type(8))) short  s16x8;
typedef __attribute__((ext_vector_type(4))) short  s16x4;
typedef __attribute__((ext_vector_type(8))) __bf16 bf16x8;
typedef __attribute__((ext_vector_type(4))) float  f32x4;

__device__ __forceinline__ short f2b(float x) {
  unsigned u = __builtin_bit_cast(unsigned, x);
  unsigned r = (u + 0x7FFFu + ((u >> 16) & 1u)) >> 16;
  return (short)r;
}
__device__ __forceinline__ float b2f(short s) {
  unsigned u = ((unsigned)(unsigned short)s) << 16;
  return __builtin_bit_cast(float, u);
}

__device__ __forceinline__ void load_lds16(const short* g, short* lds) {
  __builtin_amdgcn_global_load_lds(
      (const __attribute__((address_space(1))) void*)g,
      (__attribute__((address_space(3))) void*)lds, 16, 0, 0);
}

__device__ __forceinline__ f32x4 mfma_bf16(s16x8 a, s16x8 b, f32x4 c) {
  return __builtin_amdgcn_mfma_f32_16x16x32_bf16(
      __builtin_bit_cast(bf16x8, a), __builtin_bit_cast(bf16x8, b), c, 0, 0, 0);
}

// ---------------------------------------------------------------------------
// 128x128 tile GEMM, C = A * B(NxK row-major)^T.  K multiple of 64.
// acc[i][j][r] = C[m0+wm+i*16+(lane>>4)*4+r][n0+wn+j*16+(lane&15)]
// ---------------------------------------------------------------------------
__device__ __forceinline__ void gemm_core(short* As, short* Bs,
                                          const short* __restrict__ A, int ldA, int mClamp,
                                          const short* __restrict__ B, int ldB, int nClamp,
                                          int K, int m0, int n0, f32x4 acc[4][4]) {
  const int tid  = threadIdx.x;
  const int w    = tid >> 6;
  const int lane = tid & 63;
  const int lrow = lane >> 3;
  const int lcol = (lane & 7) * 8;
  const int lr   = lane & 15;
  const int lq   = lane >> 4;
  const int wm   = (w >> 1) * 64;
  const int wn   = (w & 1) * 64;

  const short* pa[4];
  const short* pb[4];
  short* la[4];
  short* lb[4];
#pragma unroll
  for (int i = 0; i < 4; ++i) {
    int row = w * 32 + i * 8 + lrow;
    int ra = m0 + row; if (ra > mClamp) ra = mClamp;
    int rb = n0 + row; if (rb > nClamp) rb = nClamp;
    pa[i] = A + (size_t)ra * ldA + lcol;
    pb[i] = B + (size_t)rb * ldB + lcol;
    la[i] = &As[(w * 32 + i * 8) * 64];
    lb[i] = &Bs[(w * 32 + i * 8) * 64];
  }

#pragma unroll
  for (int i = 0; i < 4; ++i)
#pragma unroll
    for (int j = 0; j < 4; ++j) acc[i][j] = (f32x4){0.f, 0.f, 0.f, 0.f};

  for (int k0 = 0; k0 < K; k0 += 64) {
#pragma unroll
    for (int i = 0; i < 4; ++i) {
      load_lds16(pa[i] + k0, la[i]);
      load_lds16(pb[i] + k0, lb[i]);
    }
    __syncthreads();
#pragma unroll
    for (int kk = 0; kk < 2; ++kk) {
      s16x8 af[4], bf[4];
#pragma unroll
      for (int f = 0; f < 4; ++f)
        af[f] = *(const s16x8*)&As[(wm + f * 16 + lr) * 64 + kk * 32 + lq * 8];
#pragma unroll
      for (int f = 0; f < 4; ++f)
        bf[f] = *(const s16x8*)&Bs[(wn + f * 16 + lr) * 64 + kk * 32 + lq * 8];
#pragma unroll
      for (int i = 0; i < 4; ++i)
#pragma unroll
        for (int j = 0; j < 4; ++j)
          acc[i][j] = mfma_bf16(af[i], bf[j], acc[i][j]);
    }
    __syncthreads();
  }
}

// ---------------------------------------------------------------------------
// 128x256 tile GEMM.  As: 128*64 shorts, Bs: 256*64 shorts.
// acc[i][j][r] = C[m0+(w>>1)*64+i*16+(lane>>4)*4+r][n0+(w&1)*128+j*16+(lane&15)]
// ---------------------------------------------------------------------------
__device__ __forceinline__ void gemm_core256(short* As, short* Bs,
                                             const short* __restrict__ A, int ldA, int mClamp,
                                             const short* __restrict__ B, int ldB, int nClamp,
                                             int K, int m0, int n0, f32x4 acc[4][8]) {
  const int tid  = threadIdx.x;
  const int w    = tid >> 6;
  const int lane = tid & 63;
  const int lrow = lane >> 3;
  const int lcol = (lane & 7) * 8;
  const int lr   = lane & 15;
  const int lq   = lane >> 4;
  const int wm   = (w >> 1) * 64;
  const int wn   = (w & 1) * 128;

  const short* pa[4];
  short* la[4];
  const short* pb[8];
  short* lb[8];
#pragma unroll
  for (int i = 0; i < 4; ++i) {
    int row = w * 32 + i * 8 + lrow;
    int ra = m0 + row; if (ra > mClamp) ra = mClamp;
    pa[i] = A + (size_t)ra * ldA + lcol;
    la[i] = &As[(w * 32 + i * 8) * 64];
  }
#pragma unroll
  for (int i = 0; i < 8; ++i) {
    int row = w * 64 + i * 8 + lrow;
    int rb = n0 + row; if (rb > nClamp) rb = nClamp;
    pb[i] = B + (size_t)rb * ldB + lcol;
    lb[i] = &Bs[(w * 64 + i * 8) * 64];
  }

#pragma unroll
  for (int i = 0; i < 4; ++i)
#pragma unroll
    for (int j = 0; j < 8; ++j) acc[i][j] = (f32x4){0.f, 0.f, 0.f, 0.f};

  for (int k0 = 0; k0 < K; k0 += 64) {
#pragma unroll
    for (int i = 0; i < 4; ++i) load_lds16(pa[i] + k0, la[i]);
#pragma unroll
    for (int i = 0; i < 8; ++i) load_lds16(pb[i] + k0, lb[i]);
    __syncthreads();
#pragma unroll
    for (int kk = 0; kk < 2; ++kk) {
      s16x8 af[4], bf[8];
#pragma unroll
      for (int f = 0; f < 4; ++f)
        af[f] = *(const s16x8*)&As[(wm + f * 16 + lr) * 64 + kk * 32 + lq * 8];
#pragma unroll
      for (int f = 0; f < 8; ++f)
        bf[f] = *(const s16x8*)&Bs[(wn + f * 16 + lr) * 64 + kk * 32 + lq * 8];
#pragma unroll
      for (int i = 0; i < 4; ++i)
#pragma unroll
        for (int j = 0; j < 8; ++j)
          acc[i][j] = mfma_bf16(af[i], bf[j], acc[i][j]);
    }
    __syncthreads();
  }
}

// ---------------------------------------------------------------------------
__global__ void k_cast(const float* __restrict__ X, short* __restrict__ O, int n4) {
  int i = blockIdx.x * blockDim.x + threadIdx.x;
  if (i >= n4) return;
  float4 v = ((const float4*)X)[i];
  s16x4 o = {f2b(v.x), f2b(v.y), f2b(v.z), f2b(v.w)};
  *(s16x4*)&O[(size_t)i * 4] = o;
}

__global__ void k_transpose_w(const float* __restrict__ W0, const float* __restrict__ W1,
                              const float* __restrict__ W2, short* __restrict__ Wt) {
  const float* W = (blockIdx.z == 0) ? W0 : ((blockIdx.z == 1) ? W1 : W2);
  short* O = Wt + (size_t)blockIdx.z * DMODEL * DMODEL;
  __shared__ float t[32][33];
  int tx = threadIdx.x, ty = threadIdx.y;
  int n0 = blockIdx.x * 32, k0 = blockIdx.y * 32;
#pragma unroll
  for (int i = 0; i < 4; ++i)
    t[ty + i * 8][tx] = W[(size_t)(k0 + ty + i * 8) * DMODEL + n0 + tx];
  __syncthreads();
#pragma unroll
  for (int i = 0; i < 4; ++i)
    O[(size_t)(n0 + ty + i * 8) * DMODEL + k0 + tx] = f2b(t[tx][ty + i * 8]);
}

__global__ void k_zero_vtpad(short* __restrict__ Vt) {
  int idx = blockIdx.x * blockDim.x + threadIdx.x;
  if (idx >= NBH * HD * (KPAD - S_LEN)) return;
  int bhd = idx / (KPAD - S_LEN);
  int s = S_LEN + idx - bhd * (KPAD - S_LEN);
  Vt[(size_t)bhd * KPAD + s] = 0;
}

// ---------------------------------------------------------------------------
// QKV: 128x256 tiles, grid (348,1,3).  XCD swizzle: blocks with t%8==x land on
// XCD x (8 XCDs, grid.x divisible granularity); all 6 n-columns of one m-tile
// share t%8 -> one X tile stays L2-resident per XCD while W streams.
__global__ __launch_bounds__(256, 2) void k_gemm_qkv(const short* __restrict__ Xb,
                                                     const short* __restrict__ Wt,
                                                     short* __restrict__ out16,
                                                     short* __restrict__ Vt) {
  __shared__ short smem[24576];   // As 8192 + Bs 16384; epilogue reuses 16896
  const int z = blockIdx.z;
  int t = blockIdx.x;
  int m_idx, n_idx;
  if (t < 336) { int band = t / 48, loc = t - band * 48;
                 m_idx = band * 8 + (loc & 7); n_idx = loc >> 3; }
  else         { int u = t - 336; m_idx = 56 + (u & 1); n_idx = u >> 1; }
  const int m0 = m_idx * 128, n0 = n_idx * 256;

  f32x4 acc[4][8];
  gemm_core256(smem, smem + 8192, Xb, DMODEL, MTOT - 1,
               Wt + (size_t)z * DMODEL * DMODEL, DMODEL, DMODEL - 1,
               DMODEL, m0, n0, acc);

  const int tid = threadIdx.x, w = tid >> 6, lane = tid & 63;
  const int lr = lane & 15, lq = lane >> 4;
  const int wm = (w >> 1) * 64, wn = (w & 1) * 128;

  if (z == 2) {
    // transpose each 128-wide n-half through LDS (stride 132), store Vt rows.
    short* T16 = smem;
    const int m_local_s = tid & 127, h2 = tid >> 7;
    for (int half = 0; half < 2; ++half) {
      if ((w & 1) == half) {
#pragma unroll
        for (int i = 0; i < 4; ++i)
#pragma unroll
          for (int j = 0; j < 8; ++j) {
            int nl = j * 16 + lr;            // [0,128)
#pragma unroll
            for (int r = 0; r < 4; ++r)
              T16[nl * 132 + wm + i * 16 + lq * 4 + r] = f2b(acc[i][j][r]);
          }
      }
      __syncthreads();
      const int m = m0 + m_local_s;
      if (m < MTOT) {
        const int b = m / S_LEN, s = m - b * S_LEN;
        for (int p = 0; p < 64; ++p) {
          int nl = p * 2 + h2;
          int n = n0 + half * 128 + nl;
          int h = n / HD, d = n - h * HD;
          Vt[(((size_t)(b * NH + h)) * HD + d) * KPAD + s] = T16[nl * 132 + m_local_s];
        }
      }
      __syncthreads();
    }
  } else {
    const float inv = 0.05103103630798287f;  // 1/sqrt(384)
#pragma unroll
    for (int i = 0; i < 4; ++i)
#pragma unroll
      for (int j = 0; j < 8; ++j) {
        int n = n0 + wn + j * 16 + lr;
#pragma unroll
        for (int r = 0; r < 4; ++r) {
          int m = m0 + wm + i * 16 + lq * 4 + r;
          if (m >= MTOT) continue;
          float v = acc[i][j][r];
          int b = m / S_LEN, s = m - b * S_LEN;
          short* dst = out16 + (size_t)(b >> 1) * CHS + (size_t)(b & 1) * BSLAB +
                       (z == 1 ? KOFF : 0UL);
          dst[(size_t)s * DMODEL + n] = f2b(z == 0 ? v * inv : v);
        }
      }
  }
}

// T = Q @ E^T stored PACKED: Tp[m][n] = T[m][n - m + 919] (n = key index).
// Only band tiles 6 <= i+j <= 14 produce in-range packed cols.  Grid (71,1,CH).
__global__ __launch_bounds__(256) void k_gemm_T(const short* __restrict__ out16,
                                                const short* __restrict__ Eb,
                                                short* __restrict__ Tp, int bh0) {
  __shared__ short smem[16384];
  const int z = blockIdx.z;
  const int bh = bh0 + z, b = bh >> 2, h = bh & 3;
  int t = blockIdx.x;
  int i_idx, j_idx;
  if (t < 7) { i_idx = t; j_idx = 6 - t; }
  else { int u = t - 7; int s = 7 + (u >> 3); i_idx = u & 7; j_idx = s - i_idx; }
  const int m0 = i_idx * 128, n0 = j_idx * 128;
  const short* A = out16 + (size_t)(b >> 1) * CHS + (size_t)(b & 1) * BSLAB + h * HD;
  f32x4 acc[4][4];
  gemm_core(smem, smem + 8192, A, DMODEL, S_LEN - 1, Eb, HD, LREL - 1, HD, m0, n0, acc);
  const int tid = threadIdx.x, w = tid >> 6, lane = tid & 63;
  const int lr = lane & 15, lq = lane >> 4;
  const int wm = (w >> 1) * 64, wn = (w & 1) * 64;
#pragma unroll
  for (int i = 0; i < 4; ++i)
#pragma unroll
    for (int j = 0; j < 4; ++j) {
      int l = n0 + wn + j * 16 + lr;           // rel-pos index
#pragma unroll
      for (int r = 0; r < 4; ++r) {
        int m = m0 + wm + i * 16 + lq * 4 + r;
        if (m < S_LEN) {
          int jp = l - (S_LEN - 1) + m;        // key index
          if (jp >= 0 && jp < S_LEN)
            Tp[((size_t)z * S_LEN + m) * S_LEN + jp] = f2b(acc[i][j][r]);
        }
      }
    }
}

// scores: 128x256 tiles, bias read is a plain coalesced Tp row.  Grid (8,4,CH).
__global__ __launch_bounds__(256, 2) void k_gemm_scores(const short* __restrict__ out16,
                                                        const short* __restrict__ Tp,
                                                        float* __restrict__ SCc, int bh0) {
  __shared__ short smem[24576];
  const int z = blockIdx.z;
  const int bh = bh0 + z, b = bh >> 2, h = bh & 3;
  const int m0 = blockIdx.x * 128, n0 = blockIdx.y * 256;
  const short* Qp = out16 + (size_t)(b >> 1) * CHS + (size_t)(b & 1) * BSLAB + h * HD;
  const short* Kp = Qp + KOFF;
  f32x4 acc[4][8];
  gemm_core256(smem, smem + 8192, Qp, DMODEL, S_LEN - 1, Kp, DMODEL, S_LEN - 1,
               HD, m0, n0, acc);
  const int tid = threadIdx.x, w = tid >> 6, lane = tid & 63;
  const int lr = lane & 15, lq = lane >> 4;
  const int wm = (w >> 1) * 64, wn = (w & 1) * 128;
#pragma unroll
  for (int i = 0; i < 4; ++i)
#pragma unroll
    for (int j = 0; j < 8; ++j) {
      int n = n0 + wn + j * 16 + lr;
#pragma unroll
      for (int r = 0; r < 4; ++r) {
        int m = m0 + wm + i * 16 + lq * 4 + r;
        if (m < S_LEN && n < S_LEN) {
          SCc[((size_t)z * S_LEN + m) * S_LEN + n] =
              acc[i][j][r] + b2f(Tp[((size_t)z * S_LEN + m) * S_LEN + n]);
        }
      }
    }
}

// softmax IN PLACE: reads 920 fp32 of a SC row, writes 960 bf16 probs into the
// first 1920 bytes of the same row (all reads precede writes via barriers).
__global__ __launch_bounds__(256) void k_softmax(float* __restrict__ SCc) {
  const int row = blockIdx.x;               // z*920 + q
  float* src = SCc + (size_t)row * S_LEN;
  short* dst = (short*)src;                 // stride PRLD row, in place
  const int tid = threadIdx.x, lane = tid & 63, wv = tid >> 6;
  float v[4];
#pragma unroll
  for (int i = 0; i < 4; ++i) {
    int k = i * 256 + tid;
    v[i] = (k < S_LEN) ? src[k] : -1e30f;
  }
  float mx = fmaxf(fmaxf(v[0], v[1]), fmaxf(v[2], v[3]));
  for (int off = 32; off; off >>= 1) mx = fmaxf(mx, __shfl_xor(mx, off));
  __shared__ float redm[4];
  __shared__ float reds[4];
  if (lane == 0) redm[wv] = mx;
  __syncthreads();
  mx = fmaxf(fmaxf(redm[0], redm[1]), fmaxf(redm[2], redm[3]));
  float e[4], s = 0.f;
#pragma unroll
  for (int i = 0; i < 4; ++i) { e[i] = __expf(v[i] - mx); s += e[i]; }
  for (int off = 32; off; off >>= 1) s += __shfl_xor(s, off);
  if (lane == 0) reds[wv] = s;
  __syncthreads();
  s = reds[0] + reds[1] + reds[2] + reds[3];
  float rs = 1.0f / s;
#pragma unroll
  for (int i = 0; i < 4; ++i) {
    int k = i * 256 + tid;
    if (k < KPAD) dst[k] = f2b(k < S_LEN ? e[i] * rs : 0.f);
  }
}

__global__ __launch_bounds__(256) void k_gemm_ctx(const short* __restrict__ PRc,
                                                  const short* __restrict__ Vt,
                                                  float* __restrict__ out, int bh0) {
  __shared__ short smem[16384];
  const int z = blockIdx.z;
  const int bh = bh0 + z, b = bh >> 2, h = bh & 3;
  const int m0 = blockIdx.x * 128, n0 = blockIdx.y * 128;
  const short* A = PRc + (size_t)z * S_LEN * PRLD;
  const short* Bt = Vt + (size_t)bh * HD * KPAD;
  f32x4 acc[4][4];
  gemm_core(smem, smem + 8192, A, PRLD, S_LEN - 1, Bt, KPAD, HD - 1, KPAD, m0, n0, acc);
  const int tid = threadIdx.x, w = tid >> 6, lane = tid & 63;
  const int lr = lane & 15, lq = lane >> 4;
  const int wm = (w >> 1) * 64, wn = (w & 1) * 64;
#pragma unroll
  for (int i = 0; i < 4; ++i)
#pragma unroll
    for (int j = 0; j < 4; ++j) {
      int n = n0 + wn + j * 16 + lr;
#pragma unroll
      for (int r = 0; r < 4; ++r) {
        int m = m0 + wm + i * 16 + lq * 4 + r;
        if (m < S_LEN)
          out[((size_t)(b * S_LEN) + m) * DMODEL + h * HD + n] = acc[i][j][r];
      }
    }
}

// ---------------------------------------------------------------------------
extern "C" void kernel_launch(void* const* d_in, const int* in_sizes, int n_in,
                              void* d_out, int out_size, void* d_ws, size_t ws_size,
                              hipStream_t stream) {
  const float* hs = (const float*)d_in[0];
  const float* wq = (const float*)d_in[1];
  const float* wk = (const float*)d_in[2];
  const float* wv = (const float*)d_in[3];
  const float* de = (const float*)d_in[4];
  char* ws = (char*)d_ws;

  int CH;
  if      (ws_size >= 32 * CHBH + EB_BYTES + VT_BYTES) CH = 32;   // 187.5 MB
  else if (ws_size >= 16 * CHBH + EB_BYTES + VT_BYTES) CH = 16;   // 106.3 MB
  else                                                  CH = 8;   //  65.6 MB
  size_t chunk_bytes = (size_t)CH * CHBH;
  size_t fixed_base = chunk_bytes > QKV_SCRATCH ? chunk_bytes : QKV_SCRATCH;

  short* Xb  = (short*)(ws + 0);
  short* Wt  = (short*)(ws + 22609920UL);
  short* Tp  = (short*)(ws + 0);                         // aliases Xb/Wt (dead)
  float* SCc = (float*)(ws + (size_t)CH * TP_BH);
  short* PRc = (short*)SCc;                              // softmax is in-place
  short* Eb  = (short*)(ws + fixed_base);
  short* Vt  = (short*)(ws + fixed_base + EB_BYTES);
  short* out16 = (short*)d_out;

  k_cast<<<(MTOT * DMODEL / 4 + 255) / 256, 256, 0, stream>>>(hs, Xb, MTOT * DMODEL / 4);
  k_cast<<<(LREL * HD / 4 + 255) / 256, 256, 0, stream>>>(de, Eb, LREL * HD / 4);
  k_transpose_w<<<dim3(48, 48, 3), dim3(32, 8, 1), 0, stream>>>(wq, wk, wv, Wt);
  k_zero_vtpad<<<(NBH * HD * (KPAD - S_LEN) + 255) / 256, 256, 0, stream>>>(Vt);

  k_gemm_qkv<<<dim3(348, 1, 3), 256, 0, stream>>>(Xb, Wt, out16, Vt);

  int NC = 32 / CH;
  for (int c = 0; c < NC; ++c) {
    int bh0 = c * CH;
    k_gemm_T<<<dim3(71, 1, CH), 256, 0, stream>>>(out16, Eb, Tp, bh0);
    k_gemm_scores<<<dim3(8, 4, CH), 256, 0, stream>>>(out16, Tp, SCc, bh0);
    k_softmax<<<CH * S_LEN, 256, 0, stream>>>(SCc);
    k_gemm_ctx<<<dim3(8, 3, CH), 256, 0, stream>>>(PRc, Vt, (float*)d_out, bh0);
  }
}